// Round 2
// baseline (777.845 us; speedup 1.0000x reference)
//
#include <hip/hip_runtime.h>

#define N_NODES 50000

// deg[i] += 1 for each edge with dst==i
__global__ void deg_kernel(const int* __restrict__ dst, int E, float* __restrict__ deg) {
    int e = blockIdx.x * blockDim.x + threadIdx.x;
    if (e < E) atomicAdd(&deg[dst[e]], 1.0f);
}

__global__ void rsqrt_kernel(float* __restrict__ deg, int n) {
    int i = blockIdx.x * blockDim.x + threadIdx.x;
    if (i < n) deg[i] = rsqrtf(deg[i] + 1.0f);
}

// Y[row, j] = sum_k X[row,k] * W[k,j] (+bias) (+relu). One 64-thread group per row.
template<int K, int NOUT, bool RELU, bool BIAS>
__global__ void mm_kernel(const float* __restrict__ X, const float* __restrict__ W,
                          const float* __restrict__ bias, float* __restrict__ Y, int n) {
    constexpr int ROWS = 4;           // 4 rows per 256-thread block
    __shared__ float xs[ROWS][K];
    const int tid = threadIdx.x;
    const int r = tid >> 6, j = tid & 63;
    const int row = blockIdx.x * ROWS + r;
    if (row < n) {
        for (int k = j; k < K; k += 64) xs[r][k] = X[row * K + k];
    }
    __syncthreads();
    if (row < n && j < NOUT) {
        float acc = BIAS ? bias[j] : 0.0f;
        #pragma unroll
        for (int k = 0; k < K; ++k) acc = fmaf(xs[r][k], W[k * NOUT + j], acc);
        if (RELU) acc = fmaxf(acc, 0.0f);
        Y[row * NOUT + j] = acc;
    }
}

// One wave per edge: lanes 0..63 handle the 64 features.
__global__ void agg_kernel(const float* __restrict__ h, const int* __restrict__ src,
                           const int* __restrict__ dst, const float* __restrict__ dis,
                           float* __restrict__ agg, int E) {
    int t = blockIdx.x * 256 + threadIdx.x;
    int e = t >> 6, j = t & 63;
    if (e < E) {
        int s = src[e], d = dst[e];
        float norm = dis[s] * dis[d];
        atomicAdd(&agg[d * 64 + j], h[s * 64 + j] * norm);
    }
}

// agg = relu(agg + dis^2 * h + b)
__global__ void finalize_kernel(const float* __restrict__ h, const float* __restrict__ b,
                                const float* __restrict__ dis, float* __restrict__ agg, int n64) {
    int t = blockIdx.x * 256 + threadIdx.x;
    if (t < n64) {
        int i = t >> 6, j = t & 63;
        float d = dis[i];
        float v = agg[t] + d * d * h[t] + b[j];
        agg[t] = fmaxf(v, 0.0f);
    }
}

extern "C" void kernel_launch(void* const* d_in, const int* in_sizes, int n_in,
                              void* d_out, int out_size, void* d_ws, size_t ws_size,
                              hipStream_t stream) {
    const float* x   = (const float*)d_in[0];
    const int*   ei  = (const int*)d_in[1];
    const float* W1  = (const float*)d_in[2];
    const float* b1  = (const float*)d_in[3];
    const float* W2  = (const float*)d_in[4];
    const float* b2  = (const float*)d_in[5];
    const float* W3  = (const float*)d_in[6];
    const float* b3  = (const float*)d_in[7];
    const float* Wf1 = (const float*)d_in[8];
    const float* bf1 = (const float*)d_in[9];
    const float* Wf2 = (const float*)d_in[10];
    const float* bf2 = (const float*)d_in[11];
    float* out = (float*)d_out;

    const int N = N_NODES;
    const int E = in_sizes[1] / 2;
    const int* src = ei;
    const int* dst = ei + E;

    float* ws  = (float*)d_ws;
    float* dis = ws;               // N floats (padded region of 50176)
    float* A   = ws + 50176;       // N*64
    float* B   = A + (size_t)N * 64;

    // degree + rsqrt
    hipMemsetAsync(dis, 0, (size_t)N * sizeof(float), stream);
    deg_kernel<<<(E + 255) / 256, 256, 0, stream>>>(dst, E, dis);
    rsqrt_kernel<<<(N + 255) / 256, 256, 0, stream>>>(dis, N);

    const int mmGrid  = (N + 3) / 4;
    const int aggGrid = (int)(((long long)E * 64 + 255) / 256);
    const int finGrid = (N * 64 + 255) / 256;

    // ---- Layer 1: h1 = x@W1 ; agg ; relu(agg + dis^2*h1 + b1) -> B ----
    mm_kernel<128, 64, false, false><<<mmGrid, 256, 0, stream>>>(x, W1, nullptr, A, N);
    hipMemsetAsync(B, 0, (size_t)N * 64 * sizeof(float), stream);
    agg_kernel<<<aggGrid, 256, 0, stream>>>(A, src, dst, dis, B, E);
    finalize_kernel<<<finGrid, 256, 0, stream>>>(A, b1, dis, B, N * 64);

    // ---- Layer 2 ----
    mm_kernel<64, 64, false, false><<<mmGrid, 256, 0, stream>>>(B, W2, nullptr, A, N);
    hipMemsetAsync(B, 0, (size_t)N * 64 * sizeof(float), stream);
    agg_kernel<<<aggGrid, 256, 0, stream>>>(A, src, dst, dis, B, E);
    finalize_kernel<<<finGrid, 256, 0, stream>>>(A, b2, dis, B, N * 64);

    // ---- Layer 3 ----
    mm_kernel<64, 64, false, false><<<mmGrid, 256, 0, stream>>>(B, W3, nullptr, A, N);
    hipMemsetAsync(B, 0, (size_t)N * 64 * sizeof(float), stream);
    agg_kernel<<<aggGrid, 256, 0, stream>>>(A, src, dst, dis, B, E);
    finalize_kernel<<<finGrid, 256, 0, stream>>>(A, b3, dis, B, N * 64);

    // ---- FFN head ----
    mm_kernel<64, 64, true, true><<<mmGrid, 256, 0, stream>>>(B, Wf1, bf1, A, N);
    mm_kernel<64, 10, false, true><<<mmGrid, 256, 0, stream>>>(A, Wf2, bf2, out, N);
}

// Round 3
// 449.861 us; speedup vs baseline: 1.7291x; 1.7291x over previous
//
#include <hip/hip_runtime.h>

#define N_NODES 50000
#define NPAD 50176   // padded node count (multiple of 1024)

// ---- CSR build ----
__global__ void cnt_kernel(const int* __restrict__ dst, int E, int* __restrict__ cnt) {
    int e = blockIdx.x * blockDim.x + threadIdx.x;
    if (e < E) atomicAdd(&cnt[dst[e]], 1);
}

__global__ void dis_kernel(const int* __restrict__ cnt, float* __restrict__ dis, int n) {
    int i = blockIdx.x * blockDim.x + threadIdx.x;
    if (i < n) dis[i] = rsqrtf((float)cnt[i] + 1.0f);
}

// Single-block exclusive scan of cnt[0..N) -> rowptr & cursor; rowptr[N]=E.
__global__ __launch_bounds__(1024) void scan_kernel(const int* __restrict__ cnt,
                                                    int* __restrict__ rowptr,
                                                    int* __restrict__ cursor, int n) {
    __shared__ int partial[1024];
    const int tid = threadIdx.x;
    const int C = (n + 1023) / 1024;
    const int lo = tid * C, hi = min(lo + C, n);
    int s = 0;
    for (int i = lo; i < hi; ++i) s += cnt[i];
    partial[tid] = s;
    __syncthreads();
    // inclusive Hillis-Steele
    for (int off = 1; off < 1024; off <<= 1) {
        int v = (tid >= off) ? partial[tid - off] : 0;
        __syncthreads();
        partial[tid] += v;
        __syncthreads();
    }
    int run = (tid > 0) ? partial[tid - 1] : 0;   // exclusive base for this chunk
    for (int i = lo; i < hi; ++i) {
        rowptr[i] = run;
        cursor[i] = run;
        run += cnt[i];
    }
    if (tid == 1023) rowptr[n] = partial[1023];
}

__global__ void fill_kernel(const int* __restrict__ src, const int* __restrict__ dst,
                            int E, int* __restrict__ cursor, int* __restrict__ col) {
    int e = blockIdx.x * blockDim.x + threadIdx.x;
    if (e < E) {
        int pos = atomicAdd(&cursor[dst[e]], 1);
        col[pos] = src[e];
    }
}

// ---- dense MM: Y[row,j] = (sum_k X[row,k]*W[k,j] [+bias]) [*dis[row]] [relu] ----
template<int K, int NOUT, bool RELU, bool BIAS, bool SCALE>
__global__ void mm_kernel(const float* __restrict__ X, const float* __restrict__ W,
                          const float* __restrict__ bias, const float* __restrict__ dis,
                          float* __restrict__ Y, int n) {
    constexpr int ROWS = 4;
    __shared__ float xs[ROWS][K];
    const int tid = threadIdx.x;
    const int r = tid >> 6, j = tid & 63;
    const int row = blockIdx.x * ROWS + r;
    if (row < n) {
        for (int k = j; k < K; k += 64) xs[r][k] = X[row * K + k];
    }
    __syncthreads();
    if (row < n && j < NOUT) {
        float acc = BIAS ? bias[j] : 0.0f;
        #pragma unroll
        for (int k = 0; k < K; ++k) acc = fmaf(xs[r][k], W[k * NOUT + j], acc);
        if (SCALE) acc *= dis[row];
        if (RELU) acc = fmaxf(acc, 0.0f);
        Y[row * NOUT + j] = acc;
    }
}

// ---- CSR aggregate + finalize: out[d,j] = relu(dis[d]*(sum_in hp[s,j] + hp[d,j]) + b[j])
__global__ void csr_agg_kernel(const float* __restrict__ hp, const int* __restrict__ rowptr,
                               const int* __restrict__ col, const float* __restrict__ dis,
                               const float* __restrict__ b, float* __restrict__ out, int n) {
    const int tid = threadIdx.x;
    const int w = tid >> 6, j = tid & 63;
    const int d = blockIdx.x * 4 + w;
    if (d >= n) return;
    const int beg = rowptr[d], end = rowptr[d + 1];
    const int deg = end - beg;
    float acc = hp[(size_t)d * 64 + j];   // self-loop term
    int base = 0;
    while (base < deg) {
        int idx = base + j;
        int c = (idx < deg) ? col[beg + idx] : 0;
        int m = min(64, deg - base);
        int e = 0;
        for (; e + 8 <= m; e += 8) {
            int s0 = __shfl(c, e + 0), s1 = __shfl(c, e + 1);
            int s2 = __shfl(c, e + 2), s3 = __shfl(c, e + 3);
            int s4 = __shfl(c, e + 4), s5 = __shfl(c, e + 5);
            int s6 = __shfl(c, e + 6), s7 = __shfl(c, e + 7);
            float v0 = hp[(size_t)s0 * 64 + j], v1 = hp[(size_t)s1 * 64 + j];
            float v2 = hp[(size_t)s2 * 64 + j], v3 = hp[(size_t)s3 * 64 + j];
            float v4 = hp[(size_t)s4 * 64 + j], v5 = hp[(size_t)s5 * 64 + j];
            float v6 = hp[(size_t)s6 * 64 + j], v7 = hp[(size_t)s7 * 64 + j];
            acc += ((v0 + v1) + (v2 + v3)) + ((v4 + v5) + (v6 + v7));
        }
        for (; e < m; ++e) {
            int s = __shfl(c, e);
            acc += hp[(size_t)s * 64 + j];
        }
        base += 64;
    }
    out[(size_t)d * 64 + j] = fmaxf(dis[d] * acc + b[j], 0.0f);
}

extern "C" void kernel_launch(void* const* d_in, const int* in_sizes, int n_in,
                              void* d_out, int out_size, void* d_ws, size_t ws_size,
                              hipStream_t stream) {
    const float* x   = (const float*)d_in[0];
    const int*   ei  = (const int*)d_in[1];
    const float* W1  = (const float*)d_in[2];
    const float* b1  = (const float*)d_in[3];
    const float* W2  = (const float*)d_in[4];
    const float* b2  = (const float*)d_in[5];
    const float* W3  = (const float*)d_in[6];
    const float* b3  = (const float*)d_in[7];
    const float* Wf1 = (const float*)d_in[8];
    const float* bf1 = (const float*)d_in[9];
    const float* Wf2 = (const float*)d_in[10];
    const float* bf2 = (const float*)d_in[11];
    float* out = (float*)d_out;

    const int N = N_NODES;
    const int E = in_sizes[1] / 2;
    const int* src = ei;
    const int* dst = ei + E;

    // workspace layout (all 4-byte elements)
    char* p = (char*)d_ws;
    int*   cnt    = (int*)p;                 p += (size_t)NPAD * 4;
    float* dis    = (float*)p;               p += (size_t)NPAD * 4;
    int*   rowptr = (int*)p;                 p += (size_t)(NPAD + 64) * 4;
    int*   cursor = (int*)p;                 p += (size_t)NPAD * 4;
    int*   col    = (int*)p;                 p += (size_t)E * 4;
    float* A      = (float*)p;               p += (size_t)N * 64 * 4;
    float* B      = (float*)p;

    // ---- CSR build + norms ----
    hipMemsetAsync(cnt, 0, (size_t)N * sizeof(int), stream);
    cnt_kernel<<<(E + 255) / 256, 256, 0, stream>>>(dst, E, cnt);
    dis_kernel<<<(N + 255) / 256, 256, 0, stream>>>(cnt, dis, N);
    scan_kernel<<<1, 1024, 0, stream>>>(cnt, rowptr, cursor, N);
    fill_kernel<<<(E + 255) / 256, 256, 0, stream>>>(src, dst, E, cursor, col);

    const int mmGrid  = (N + 3) / 4;
    const int aggGrid = (N + 3) / 4;

    // ---- Layer 1: A = dis*(x@W1) ; B = relu(dis*(agg+self)+b1) ----
    mm_kernel<128, 64, false, false, true><<<mmGrid, 256, 0, stream>>>(x, W1, nullptr, dis, A, N);
    csr_agg_kernel<<<aggGrid, 256, 0, stream>>>(A, rowptr, col, dis, b1, B, N);

    // ---- Layer 2 ----
    mm_kernel<64, 64, false, false, true><<<mmGrid, 256, 0, stream>>>(B, W2, nullptr, dis, A, N);
    csr_agg_kernel<<<aggGrid, 256, 0, stream>>>(A, rowptr, col, dis, b2, B, N);

    // ---- Layer 3 ----
    mm_kernel<64, 64, false, false, true><<<mmGrid, 256, 0, stream>>>(B, W3, nullptr, dis, A, N);
    csr_agg_kernel<<<aggGrid, 256, 0, stream>>>(A, rowptr, col, dis, b3, B, N);

    // ---- FFN head ----
    mm_kernel<64, 64, true, true, false><<<mmGrid, 256, 0, stream>>>(B, Wf1, bf1, nullptr, A, N);
    mm_kernel<64, 10, false, true, false><<<mmGrid, 256, 0, stream>>>(A, Wf2, bf2, nullptr, out, N);
}

// Round 4
// 351.366 us; speedup vs baseline: 2.2138x; 1.2803x over previous
//
#include <hip/hip_runtime.h>

#define N_NODES 50000
#define SCAN_BLK 256
#define NBLK ((N_NODES + SCAN_BLK - 1) / SCAN_BLK)   // 196

// ---- CSR build ----
__global__ void cnt_kernel(const int* __restrict__ dst, int E, int* __restrict__ cnt) {
    int e = blockIdx.x * blockDim.x + threadIdx.x;
    if (e < E) atomicAdd(&cnt[dst[e]], 1);
}

__global__ void dis_kernel(const int* __restrict__ cnt, float* __restrict__ dis, int n) {
    int i = blockIdx.x * blockDim.x + threadIdx.x;
    if (i < n) dis[i] = rsqrtf((float)cnt[i] + 1.0f);
}

// step 1: per-block sums of cnt
__global__ void bsum_kernel(const int* __restrict__ cnt, int* __restrict__ bsum, int n) {
    __shared__ int sh[SCAN_BLK];
    int i = blockIdx.x * SCAN_BLK + threadIdx.x;
    sh[threadIdx.x] = (i < n) ? cnt[i] : 0;
    __syncthreads();
    for (int off = SCAN_BLK / 2; off > 0; off >>= 1) {
        if (threadIdx.x < off) sh[threadIdx.x] += sh[threadIdx.x + off];
        __syncthreads();
    }
    if (threadIdx.x == 0) bsum[blockIdx.x] = sh[0];
}

// step 2: single small block scans bsum -> exclusive bbase
__global__ void bscan_kernel(const int* __restrict__ bsum, int* __restrict__ bbase, int nblk) {
    __shared__ int sh[SCAN_BLK];
    int tid = threadIdx.x;
    int v = (tid < nblk) ? bsum[tid] : 0;
    sh[tid] = v;
    __syncthreads();
    for (int off = 1; off < SCAN_BLK; off <<= 1) {
        int t = (tid >= off) ? sh[tid - off] : 0;
        __syncthreads();
        sh[tid] += t;
        __syncthreads();
    }
    if (tid < nblk) bbase[tid] = sh[tid] - v;   // exclusive
}

// step 3: per-block exclusive scan of its chunk + bbase -> rowptr, cursor
__global__ void scatter_scan_kernel(const int* __restrict__ cnt, const int* __restrict__ bbase,
                                    int* __restrict__ rowptr, int* __restrict__ cursor, int n) {
    __shared__ int sh[SCAN_BLK];
    int tid = threadIdx.x;
    int i = blockIdx.x * SCAN_BLK + tid;
    int v = (i < n) ? cnt[i] : 0;
    sh[tid] = v;
    __syncthreads();
    for (int off = 1; off < SCAN_BLK; off <<= 1) {
        int t = (tid >= off) ? sh[tid - off] : 0;
        __syncthreads();
        sh[tid] += t;
        __syncthreads();
    }
    int excl = bbase[blockIdx.x] + sh[tid] - v;
    if (i < n) {
        rowptr[i] = excl;
        cursor[i] = excl;
        if (i == n - 1) rowptr[n] = excl + v;
    }
}

__global__ void fill_kernel(const int* __restrict__ src, const int* __restrict__ dst,
                            int E, int* __restrict__ cursor, int* __restrict__ col) {
    int e = blockIdx.x * blockDim.x + threadIdx.x;
    if (e < E) {
        int pos = atomicAdd(&cursor[dst[e]], 1);
        col[pos] = src[e];
    }
}

// ---- dense MM: Y[row,j] = (sum_k X[row,k]*W[k,j] [+bias]) [*dis[row]] [relu] ----
template<int K, int NOUT, bool RELU, bool BIAS, bool SCALE>
__global__ void mm_kernel(const float* __restrict__ X, const float* __restrict__ W,
                          const float* __restrict__ bias, const float* __restrict__ dis,
                          float* __restrict__ Y, int n) {
    constexpr int ROWS = 4;
    __shared__ float xs[ROWS][K];
    const int tid = threadIdx.x;
    const int r = tid >> 6, j = tid & 63;
    const int row = blockIdx.x * ROWS + r;
    if (row < n) {
        for (int k = j; k < K; k += 64) xs[r][k] = X[row * K + k];
    }
    __syncthreads();
    if (row < n && j < NOUT) {
        float acc = BIAS ? bias[j] : 0.0f;
        #pragma unroll
        for (int k = 0; k < K; ++k) acc = fmaf(xs[r][k], W[k * NOUT + j], acc);
        if (SCALE) acc *= dis[row];
        if (RELU) acc = fmaxf(acc, 0.0f);
        Y[row * NOUT + j] = acc;
    }
}

// ---- CSR aggregate + finalize: out[d,j] = relu(dis[d]*(sum_in hp[s,j] + hp[d,j]) + b[j])
__global__ void csr_agg_kernel(const float* __restrict__ hp, const int* __restrict__ rowptr,
                               const int* __restrict__ col, const float* __restrict__ dis,
                               const float* __restrict__ b, float* __restrict__ out, int n) {
    const int tid = threadIdx.x;
    const int w = tid >> 6, j = tid & 63;
    const int d = blockIdx.x * 4 + w;
    if (d >= n) return;
    const int beg = rowptr[d], end = rowptr[d + 1];
    const int deg = end - beg;
    float acc = hp[(size_t)d * 64 + j];   // self-loop term
    int base = 0;
    while (base < deg) {
        int idx = base + j;
        int c = (idx < deg) ? col[beg + idx] : 0;
        int m = min(64, deg - base);
        int e = 0;
        for (; e + 8 <= m; e += 8) {
            int s0 = __shfl(c, e + 0), s1 = __shfl(c, e + 1);
            int s2 = __shfl(c, e + 2), s3 = __shfl(c, e + 3);
            int s4 = __shfl(c, e + 4), s5 = __shfl(c, e + 5);
            int s6 = __shfl(c, e + 6), s7 = __shfl(c, e + 7);
            float v0 = hp[(size_t)s0 * 64 + j], v1 = hp[(size_t)s1 * 64 + j];
            float v2 = hp[(size_t)s2 * 64 + j], v3 = hp[(size_t)s3 * 64 + j];
            float v4 = hp[(size_t)s4 * 64 + j], v5 = hp[(size_t)s5 * 64 + j];
            float v6 = hp[(size_t)s6 * 64 + j], v7 = hp[(size_t)s7 * 64 + j];
            acc += ((v0 + v1) + (v2 + v3)) + ((v4 + v5) + (v6 + v7));
        }
        for (; e < m; ++e) {
            int s = __shfl(c, e);
            acc += hp[(size_t)s * 64 + j];
        }
        base += 64;
    }
    out[(size_t)d * 64 + j] = fmaxf(dis[d] * acc + b[j], 0.0f);
}

extern "C" void kernel_launch(void* const* d_in, const int* in_sizes, int n_in,
                              void* d_out, int out_size, void* d_ws, size_t ws_size,
                              hipStream_t stream) {
    const float* x   = (const float*)d_in[0];
    const int*   ei  = (const int*)d_in[1];
    const float* W1  = (const float*)d_in[2];
    const float* b1  = (const float*)d_in[3];
    const float* W2  = (const float*)d_in[4];
    const float* b2  = (const float*)d_in[5];
    const float* W3  = (const float*)d_in[6];
    const float* b3  = (const float*)d_in[7];
    const float* Wf1 = (const float*)d_in[8];
    const float* bf1 = (const float*)d_in[9];
    const float* Wf2 = (const float*)d_in[10];
    const float* bf2 = (const float*)d_in[11];
    float* out = (float*)d_out;

    const int N = N_NODES;
    const int E = in_sizes[1] / 2;
    const int* src = ei;
    const int* dst = ei + E;

    // workspace layout (all 4-byte elements)
    char* p = (char*)d_ws;
    int*   cnt    = (int*)p;                 p += (size_t)50176 * 4;
    float* dis    = (float*)p;               p += (size_t)50176 * 4;
    int*   rowptr = (int*)p;                 p += (size_t)(50176 + 64) * 4;
    int*   cursor = (int*)p;                 p += (size_t)50176 * 4;
    int*   bsum   = (int*)p;                 p += (size_t)256 * 4;
    int*   bbase  = (int*)p;                 p += (size_t)256 * 4;
    int*   col    = (int*)p;                 p += (size_t)E * 4;
    float* A      = (float*)p;               p += (size_t)N * 64 * 4;
    float* B      = (float*)p;

    // ---- CSR build + norms ----
    hipMemsetAsync(cnt, 0, (size_t)N * sizeof(int), stream);
    cnt_kernel<<<(E + 255) / 256, 256, 0, stream>>>(dst, E, cnt);
    dis_kernel<<<(N + 255) / 256, 256, 0, stream>>>(cnt, dis, N);
    bsum_kernel<<<NBLK, SCAN_BLK, 0, stream>>>(cnt, bsum, N);
    bscan_kernel<<<1, SCAN_BLK, 0, stream>>>(bsum, bbase, NBLK);
    scatter_scan_kernel<<<NBLK, SCAN_BLK, 0, stream>>>(cnt, bbase, rowptr, cursor, N);
    fill_kernel<<<(E + 255) / 256, 256, 0, stream>>>(src, dst, E, cursor, col);

    const int mmGrid  = (N + 3) / 4;
    const int aggGrid = (N + 3) / 4;

    // ---- Layer 1: A = dis*(x@W1) ; B = relu(dis*(agg+self)+b1) ----
    mm_kernel<128, 64, false, false, true><<<mmGrid, 256, 0, stream>>>(x, W1, nullptr, dis, A, N);
    csr_agg_kernel<<<aggGrid, 256, 0, stream>>>(A, rowptr, col, dis, b1, B, N);

    // ---- Layer 2 ----
    mm_kernel<64, 64, false, false, true><<<mmGrid, 256, 0, stream>>>(B, W2, nullptr, dis, A, N);
    csr_agg_kernel<<<aggGrid, 256, 0, stream>>>(A, rowptr, col, dis, b2, B, N);

    // ---- Layer 3 ----
    mm_kernel<64, 64, false, false, true><<<mmGrid, 256, 0, stream>>>(B, W3, nullptr, dis, A, N);
    csr_agg_kernel<<<aggGrid, 256, 0, stream>>>(A, rowptr, col, dis, b3, B, N);

    // ---- FFN head ----
    mm_kernel<64, 64, true, true, false><<<mmGrid, 256, 0, stream>>>(B, Wf1, bf1, nullptr, A, N);
    mm_kernel<64, 10, false, true, false><<<mmGrid, 256, 0, stream>>>(A, Wf2, bf2, nullptr, out, N);
}

// Round 5
// 289.732 us; speedup vs baseline: 2.6847x; 1.2127x over previous
//
#include <hip/hip_runtime.h>

#define N_NODES 50000
#define SCAN_BLK 256
#define NBLK ((N_NODES + SCAN_BLK - 1) / SCAN_BLK)   // 196

// ---- CSR build ----
__global__ void cnt_kernel(const int* __restrict__ dst, int E, int* __restrict__ cnt) {
    int e = blockIdx.x * blockDim.x + threadIdx.x;
    if (e < E) atomicAdd(&cnt[dst[e]], 1);
}

__global__ void dis_kernel(const int* __restrict__ cnt, float* __restrict__ dis, int n) {
    int i = blockIdx.x * blockDim.x + threadIdx.x;
    if (i < n) dis[i] = rsqrtf((float)cnt[i] + 1.0f);
}

__global__ void bsum_kernel(const int* __restrict__ cnt, int* __restrict__ bsum, int n) {
    __shared__ int sh[SCAN_BLK];
    int i = blockIdx.x * SCAN_BLK + threadIdx.x;
    sh[threadIdx.x] = (i < n) ? cnt[i] : 0;
    __syncthreads();
    for (int off = SCAN_BLK / 2; off > 0; off >>= 1) {
        if (threadIdx.x < off) sh[threadIdx.x] += sh[threadIdx.x + off];
        __syncthreads();
    }
    if (threadIdx.x == 0) bsum[blockIdx.x] = sh[0];
}

__global__ void bscan_kernel(const int* __restrict__ bsum, int* __restrict__ bbase, int nblk) {
    __shared__ int sh[SCAN_BLK];
    int tid = threadIdx.x;
    int v = (tid < nblk) ? bsum[tid] : 0;
    sh[tid] = v;
    __syncthreads();
    for (int off = 1; off < SCAN_BLK; off <<= 1) {
        int t = (tid >= off) ? sh[tid - off] : 0;
        __syncthreads();
        sh[tid] += t;
        __syncthreads();
    }
    if (tid < nblk) bbase[tid] = sh[tid] - v;   // exclusive
}

__global__ void scatter_scan_kernel(const int* __restrict__ cnt, const int* __restrict__ bbase,
                                    int* __restrict__ rowptr, int* __restrict__ cursor, int n) {
    __shared__ int sh[SCAN_BLK];
    int tid = threadIdx.x;
    int i = blockIdx.x * SCAN_BLK + tid;
    int v = (i < n) ? cnt[i] : 0;
    sh[tid] = v;
    __syncthreads();
    for (int off = 1; off < SCAN_BLK; off <<= 1) {
        int t = (tid >= off) ? sh[tid - off] : 0;
        __syncthreads();
        sh[tid] += t;
        __syncthreads();
    }
    int excl = bbase[blockIdx.x] + sh[tid] - v;
    if (i < n) {
        rowptr[i] = excl;
        cursor[i] = excl;
        if (i == n - 1) rowptr[n] = excl + v;
    }
}

__global__ void fill_kernel(const int* __restrict__ src, const int* __restrict__ dst,
                            int E, int* __restrict__ cursor, int* __restrict__ col) {
    int e = blockIdx.x * blockDim.x + threadIdx.x;
    if (e < E) {
        int pos = atomicAdd(&cursor[dst[e]], 1);
        col[pos] = src[e];
    }
}

// ---- register-blocked fp32 MM: Y = X[n,K] @ W[K,64], opt *dis[row], +bias, relu ----
// 256 threads; thread tile 4 rows x 8 cols; block tile 128 rows x 64 cols.
template<int K, bool RELU, bool BIAS, bool SCALE>
__global__ __launch_bounds__(256) void mm_tiled(const float* __restrict__ X,
        const float* __restrict__ W, const float* __restrict__ bias,
        const float* __restrict__ dis, float* __restrict__ Y, int n) {
    constexpr int KC = 32;
    __shared__ float xs[128][KC + 1];
    const int tid = threadIdx.x;
    const int j8 = tid & 7;          // col group -> cols j8*8..+7
    const int rq = tid >> 3;         // row quad -> rows rq*4..+3
    const int row0 = blockIdx.x * 128;
    const int col0 = j8 * 8;
    float acc[4][8] = {};

    for (int kc = 0; kc < K; kc += KC) {
        __syncthreads();
        #pragma unroll
        for (int it = 0; it < 4; ++it) {
            int idx = it * 256 + tid;
            int r = idx >> 3, c4 = idx & 7;
            int row = row0 + r;
            float4 v = make_float4(0.f, 0.f, 0.f, 0.f);
            if (row < n) v = *reinterpret_cast<const float4*>(&X[(size_t)row * K + kc + c4 * 4]);
            xs[r][c4 * 4 + 0] = v.x; xs[r][c4 * 4 + 1] = v.y;
            xs[r][c4 * 4 + 2] = v.z; xs[r][c4 * 4 + 3] = v.w;
        }
        __syncthreads();
        #pragma unroll 8
        for (int k = 0; k < KC; ++k) {
            const float4 w0 = *reinterpret_cast<const float4*>(&W[(size_t)(kc + k) * 64 + col0]);
            const float4 w1 = *reinterpret_cast<const float4*>(&W[(size_t)(kc + k) * 64 + col0 + 4]);
            float xv[4];
            #pragma unroll
            for (int r = 0; r < 4; ++r) xv[r] = xs[rq * 4 + r][k];
            #pragma unroll
            for (int r = 0; r < 4; ++r) {
                acc[r][0] = fmaf(xv[r], w0.x, acc[r][0]);
                acc[r][1] = fmaf(xv[r], w0.y, acc[r][1]);
                acc[r][2] = fmaf(xv[r], w0.z, acc[r][2]);
                acc[r][3] = fmaf(xv[r], w0.w, acc[r][3]);
                acc[r][4] = fmaf(xv[r], w1.x, acc[r][4]);
                acc[r][5] = fmaf(xv[r], w1.y, acc[r][5]);
                acc[r][6] = fmaf(xv[r], w1.z, acc[r][6]);
                acc[r][7] = fmaf(xv[r], w1.w, acc[r][7]);
            }
        }
    }

    float bv[8];
    if (BIAS) {
        #pragma unroll
        for (int c = 0; c < 8; ++c) bv[c] = bias[col0 + c];
    }
    #pragma unroll
    for (int r = 0; r < 4; ++r) {
        int row = row0 + rq * 4 + r;
        if (row < n) {
            float s = SCALE ? dis[row] : 1.0f;
            float o[8];
            #pragma unroll
            for (int c = 0; c < 8; ++c) {
                float v = SCALE ? acc[r][c] * s : acc[r][c];
                if (BIAS) v += bv[c];
                if (RELU) v = fmaxf(v, 0.0f);
                o[c] = v;
            }
            *reinterpret_cast<float4*>(&Y[(size_t)row * 64 + col0]) =
                make_float4(o[0], o[1], o[2], o[3]);
            *reinterpret_cast<float4*>(&Y[(size_t)row * 64 + col0 + 4]) =
                make_float4(o[4], o[5], o[6], o[7]);
        }
    }
}

// ---- fused FFN head: out = relu(X@Wf1 + bf1) @ Wf2 + bf2  (K=64, mid=64, out=10) ----
__global__ __launch_bounds__(256) void ffn_kernel(const float* __restrict__ X,
        const float* __restrict__ Wf1, const float* __restrict__ bf1,
        const float* __restrict__ Wf2, const float* __restrict__ bf2,
        float* __restrict__ out, int n) {
    constexpr int K = 64, KC = 32;
    __shared__ float xs[128][KC + 1];
    __shared__ float h1[128][65];
    const int tid = threadIdx.x;
    const int j8 = tid & 7;
    const int rq = tid >> 3;
    const int row0 = blockIdx.x * 128;
    const int col0 = j8 * 8;
    float acc[4][8] = {};

    for (int kc = 0; kc < K; kc += KC) {
        __syncthreads();
        #pragma unroll
        for (int it = 0; it < 4; ++it) {
            int idx = it * 256 + tid;
            int r = idx >> 3, c4 = idx & 7;
            int row = row0 + r;
            float4 v = make_float4(0.f, 0.f, 0.f, 0.f);
            if (row < n) v = *reinterpret_cast<const float4*>(&X[(size_t)row * K + kc + c4 * 4]);
            xs[r][c4 * 4 + 0] = v.x; xs[r][c4 * 4 + 1] = v.y;
            xs[r][c4 * 4 + 2] = v.z; xs[r][c4 * 4 + 3] = v.w;
        }
        __syncthreads();
        #pragma unroll 8
        for (int k = 0; k < KC; ++k) {
            const float4 w0 = *reinterpret_cast<const float4*>(&Wf1[(size_t)(kc + k) * 64 + col0]);
            const float4 w1 = *reinterpret_cast<const float4*>(&Wf1[(size_t)(kc + k) * 64 + col0 + 4]);
            float xv[4];
            #pragma unroll
            for (int r = 0; r < 4; ++r) xv[r] = xs[rq * 4 + r][k];
            #pragma unroll
            for (int r = 0; r < 4; ++r) {
                acc[r][0] = fmaf(xv[r], w0.x, acc[r][0]);
                acc[r][1] = fmaf(xv[r], w0.y, acc[r][1]);
                acc[r][2] = fmaf(xv[r], w0.z, acc[r][2]);
                acc[r][3] = fmaf(xv[r], w0.w, acc[r][3]);
                acc[r][4] = fmaf(xv[r], w1.x, acc[r][4]);
                acc[r][5] = fmaf(xv[r], w1.y, acc[r][5]);
                acc[r][6] = fmaf(xv[r], w1.z, acc[r][6]);
                acc[r][7] = fmaf(xv[r], w1.w, acc[r][7]);
            }
        }
    }
    // h1 = relu(acc + bf1) into LDS
    #pragma unroll
    for (int c = 0; c < 8; ++c) {
        float b = bf1[col0 + c];
        #pragma unroll
        for (int r = 0; r < 4; ++r)
            h1[rq * 4 + r][col0 + c] = fmaxf(acc[r][c] + b, 0.0f);
    }
    __syncthreads();

    // stage 2: out[row, 0..9] = h1[row,:] @ Wf2 + bf2
    const int lr = tid >> 1;      // local row 0..127
    const int ch = tid & 1;       // col half: cols ch*5..+4
    float a2[5];
    #pragma unroll
    for (int c = 0; c < 5; ++c) a2[c] = bf2[ch * 5 + c];
    #pragma unroll 8
    for (int k = 0; k < 64; ++k) {
        float xv = h1[lr][k];
        #pragma unroll
        for (int c = 0; c < 5; ++c)
            a2[c] = fmaf(xv, Wf2[(size_t)k * 10 + ch * 5 + c], a2[c]);
    }
    int row = row0 + lr;
    if (row < n) {
        #pragma unroll
        for (int c = 0; c < 5; ++c) out[(size_t)row * 10 + ch * 5 + c] = a2[c];
    }
}

// ---- CSR aggregate + finalize: out[d,j] = relu(dis[d]*(sum_in hp[s,j] + hp[d,j]) + b[j])
__global__ void csr_agg_kernel(const float* __restrict__ hp, const int* __restrict__ rowptr,
                               const int* __restrict__ col, const float* __restrict__ dis,
                               const float* __restrict__ b, float* __restrict__ out, int n) {
    const int tid = threadIdx.x;
    const int w = tid >> 6, j = tid & 63;
    const int d = blockIdx.x * 4 + w;
    if (d >= n) return;
    const int beg = rowptr[d], end = rowptr[d + 1];
    const int deg = end - beg;
    float acc = hp[(size_t)d * 64 + j];   // self-loop term
    int base = 0;
    while (base < deg) {
        int idx = base + j;
        int c = (idx < deg) ? col[beg + idx] : 0;
        int m = min(64, deg - base);
        int e = 0;
        for (; e + 8 <= m; e += 8) {
            int s0 = __shfl(c, e + 0), s1 = __shfl(c, e + 1);
            int s2 = __shfl(c, e + 2), s3 = __shfl(c, e + 3);
            int s4 = __shfl(c, e + 4), s5 = __shfl(c, e + 5);
            int s6 = __shfl(c, e + 6), s7 = __shfl(c, e + 7);
            float v0 = hp[(size_t)s0 * 64 + j], v1 = hp[(size_t)s1 * 64 + j];
            float v2 = hp[(size_t)s2 * 64 + j], v3 = hp[(size_t)s3 * 64 + j];
            float v4 = hp[(size_t)s4 * 64 + j], v5 = hp[(size_t)s5 * 64 + j];
            float v6 = hp[(size_t)s6 * 64 + j], v7 = hp[(size_t)s7 * 64 + j];
            acc += ((v0 + v1) + (v2 + v3)) + ((v4 + v5) + (v6 + v7));
        }
        for (; e < m; ++e) {
            int s = __shfl(c, e);
            acc += hp[(size_t)s * 64 + j];
        }
        base += 64;
    }
    out[(size_t)d * 64 + j] = fmaxf(dis[d] * acc + b[j], 0.0f);
}

extern "C" void kernel_launch(void* const* d_in, const int* in_sizes, int n_in,
                              void* d_out, int out_size, void* d_ws, size_t ws_size,
                              hipStream_t stream) {
    const float* x   = (const float*)d_in[0];
    const int*   ei  = (const int*)d_in[1];
    const float* W1  = (const float*)d_in[2];
    const float* b1  = (const float*)d_in[3];
    const float* W2  = (const float*)d_in[4];
    const float* b2  = (const float*)d_in[5];
    const float* W3  = (const float*)d_in[6];
    const float* b3  = (const float*)d_in[7];
    const float* Wf1 = (const float*)d_in[8];
    const float* bf1 = (const float*)d_in[9];
    const float* Wf2 = (const float*)d_in[10];
    const float* bf2 = (const float*)d_in[11];
    float* out = (float*)d_out;

    const int N = N_NODES;
    const int E = in_sizes[1] / 2;
    const int* src = ei;
    const int* dst = ei + E;

    // workspace layout (all 4-byte elements)
    char* p = (char*)d_ws;
    int*   cnt    = (int*)p;                 p += (size_t)50176 * 4;
    float* dis    = (float*)p;               p += (size_t)50176 * 4;
    int*   rowptr = (int*)p;                 p += (size_t)(50176 + 64) * 4;
    int*   cursor = (int*)p;                 p += (size_t)50176 * 4;
    int*   bsum   = (int*)p;                 p += (size_t)256 * 4;
    int*   bbase  = (int*)p;                 p += (size_t)256 * 4;
    int*   col    = (int*)p;                 p += (size_t)E * 4;
    float* A      = (float*)p;               p += (size_t)N * 64 * 4;
    float* B      = (float*)p;

    // ---- CSR build + norms ----
    hipMemsetAsync(cnt, 0, (size_t)N * sizeof(int), stream);
    cnt_kernel<<<(E + 255) / 256, 256, 0, stream>>>(dst, E, cnt);
    dis_kernel<<<(N + 255) / 256, 256, 0, stream>>>(cnt, dis, N);
    bsum_kernel<<<NBLK, SCAN_BLK, 0, stream>>>(cnt, bsum, N);
    bscan_kernel<<<1, SCAN_BLK, 0, stream>>>(bsum, bbase, NBLK);
    scatter_scan_kernel<<<NBLK, SCAN_BLK, 0, stream>>>(cnt, bbase, rowptr, cursor, N);
    fill_kernel<<<(E + 255) / 256, 256, 0, stream>>>(src, dst, E, cursor, col);

    const int mmGrid  = (N + 127) / 128;
    const int aggGrid = (N + 3) / 4;

    // ---- Layer 1 ----
    mm_tiled<128, false, false, true><<<mmGrid, 256, 0, stream>>>(x, W1, nullptr, dis, A, N);
    csr_agg_kernel<<<aggGrid, 256, 0, stream>>>(A, rowptr, col, dis, b1, B, N);

    // ---- Layer 2 ----
    mm_tiled<64, false, false, true><<<mmGrid, 256, 0, stream>>>(B, W2, nullptr, dis, A, N);
    csr_agg_kernel<<<aggGrid, 256, 0, stream>>>(A, rowptr, col, dis, b2, B, N);

    // ---- Layer 3 ----
    mm_tiled<64, false, false, true><<<mmGrid, 256, 0, stream>>>(B, W3, nullptr, dis, A, N);
    csr_agg_kernel<<<aggGrid, 256, 0, stream>>>(A, rowptr, col, dis, b3, B, N);

    // ---- fused FFN head ----
    ffn_kernel<<<mmGrid, 256, 0, stream>>>(B, Wf1, bf1, Wf2, bf2, out, N);
}